// Round 1
// baseline (400.293 us; speedup 1.0000x reference)
//
#include <hip/hip_runtime.h>
#include <hip/hip_bf16.h>

#define L_SEQ 4096
#define NB 2
#define NH 8
#define DHEAD 64
#define DMODEL 512
#define MROWS 8192

typedef __attribute__((ext_vector_type(8))) short bf16x8;
typedef __attribute__((ext_vector_type(4))) float f32x4;

#define LOG2_DECAY (-0.07400058144377693f)
#define LOG2E 1.4426950408889634f

__device__ __forceinline__ unsigned short f2b(float f) {
    __hip_bfloat16 h = __float2bfloat16(f);
    return *reinterpret_cast<unsigned short*>(&h);
}

__global__ void cast_f32_to_bf16(const float* __restrict__ src,
                                 unsigned short* __restrict__ dst, int n) {
    int i = (blockIdx.x * blockDim.x + threadIdx.x) * 4;
    if (i + 4 <= n) {
        float4 v = *reinterpret_cast<const float4*>(src + i);
        ushort4 o;
        o.x = f2b(v.x); o.y = f2b(v.y); o.z = f2b(v.z); o.w = f2b(v.w);
        *reinterpret_cast<ushort4*>(dst + i) = o;
    } else {
        for (; i < n; ++i) dst[i] = f2b(src[i]);
    }
}

// C[m][n] = sum_k X[m][k] * W[n][k] + bias[n]
// mode 0: write bf16 scattered to [B,H,L,Hd] layout (QKV proj)
// mode 1: write fp32 row-major [M][N] (output proj)
__global__ __launch_bounds__(256) void gemm_nt(const unsigned short* __restrict__ X,
                                               const unsigned short* __restrict__ W,
                                               const float* __restrict__ bias,
                                               unsigned short* __restrict__ outB,
                                               float* __restrict__ outF,
                                               int mode, int Kdim, int Ndim) {
    __shared__ __align__(16) unsigned short xs[64][72];
    __shared__ __align__(16) unsigned short wls[64][72];
    const int tid = threadIdx.x;
    const int lane = tid & 63;
    const int wave = tid >> 6;
    const int r16 = lane & 15;
    const int g = lane >> 4;
    const int m0 = blockIdx.x * 64;
    const int n0 = blockIdx.y * 64;

    f32x4 acc[4] = {};
    for (int k0 = 0; k0 < Kdim; k0 += 64) {
        __syncthreads();
#pragma unroll
        for (int i = 0; i < 2; ++i) {
            int q = tid * 2 + i;
            int row = q >> 3;
            int c8 = (q & 7) * 8;
            *reinterpret_cast<int4*>(&xs[row][c8]) =
                *reinterpret_cast<const int4*>(X + (size_t)(m0 + row) * Kdim + k0 + c8);
            *reinterpret_cast<int4*>(&wls[row][c8]) =
                *reinterpret_cast<const int4*>(W + (size_t)(n0 + row) * Kdim + k0 + c8);
        }
        __syncthreads();
        bf16x8 a0 = *reinterpret_cast<const bf16x8*>(&xs[wave * 16 + r16][8 * g]);
        bf16x8 a1 = *reinterpret_cast<const bf16x8*>(&xs[wave * 16 + r16][8 * g + 32]);
#pragma unroll
        for (int t = 0; t < 4; ++t) {
            bf16x8 b0 = *reinterpret_cast<const bf16x8*>(&wls[t * 16 + r16][8 * g]);
            bf16x8 b1 = *reinterpret_cast<const bf16x8*>(&wls[t * 16 + r16][8 * g + 32]);
            acc[t] = __builtin_amdgcn_mfma_f32_16x16x32_bf16(a0, b0, acc[t], 0, 0, 0);
            acc[t] = __builtin_amdgcn_mfma_f32_16x16x32_bf16(a1, b1, acc[t], 0, 0, 0);
        }
    }
#pragma unroll
    for (int t = 0; t < 4; ++t) {
#pragma unroll
        for (int r = 0; r < 4; ++r) {
            int m = m0 + wave * 16 + g * 4 + r;
            int n = n0 + t * 16 + r16;
            float v = acc[t][r] + bias[n];
            if (mode == 0) {
                int b = m >> 12, l = m & 4095;
                int h = n >> 6, hd = n & 63;
                outB[((size_t)(b * NH + h) * L_SEQ + l) * DHEAD + hd] = f2b(v);
            } else {
                outF[(size_t)m * Ndim + n] = v;
            }
        }
    }
}

__global__ __launch_bounds__(256) void attn_fused(const unsigned short* __restrict__ Qg,
                                                  const unsigned short* __restrict__ Kg,
                                                  const unsigned short* __restrict__ Vg,
                                                  unsigned short* __restrict__ Og) {
    __shared__ __align__(16) unsigned short ks[64][72];
    __shared__ __align__(16) unsigned short vt[64][72];   // V transposed: [d][key]
    __shared__ __align__(16) unsigned short ps[4][16][72]; // per-wave P
    const int tid = threadIdx.x;
    const int lane = tid & 63;
    const int wave = tid >> 6;
    const int r16 = lane & 15;
    const int g = lane >> 4;
    const int bh = blockIdx.y;
    const int q0 = blockIdx.x * 64;
    const size_t base = (size_t)bh * L_SEQ * DHEAD;
    const unsigned short* Qb = Qg + base;
    const unsigned short* Kb = Kg + base;
    const unsigned short* Vb = Vg + base;
    const int qrow = q0 + wave * 16;

    // Q fragments stay in registers for the whole block
    bf16x8 qa0 = *reinterpret_cast<const bf16x8*>(Qb + (size_t)(qrow + r16) * DHEAD + 8 * g);
    bf16x8 qa1 = *reinterpret_cast<const bf16x8*>(Qb + (size_t)(qrow + r16) * DHEAD + 8 * g + 32);

    f32x4 acc[4] = {};
    float mrow[4] = {-1e30f, -1e30f, -1e30f, -1e30f};
    float lrow[4] = {0.f, 0.f, 0.f, 0.f};

    for (int k0 = 0; k0 < L_SEQ; k0 += 64) {
        __syncthreads();
#pragma unroll
        for (int i = 0; i < 2; ++i) {
            int q = tid * 2 + i;
            int row = q >> 3;
            int c8 = (q & 7) * 8;
            *reinterpret_cast<int4*>(&ks[row][c8]) =
                *reinterpret_cast<const int4*>(Kb + (size_t)(k0 + row) * DHEAD + c8);
            int4 vv = *reinterpret_cast<const int4*>(Vb + (size_t)(k0 + row) * DHEAD + c8);
            int vals[4] = {vv.x, vv.y, vv.z, vv.w};
#pragma unroll
            for (int j = 0; j < 4; ++j) {
                vt[c8 + 2 * j][row] = (unsigned short)(vals[j] & 0xffff);
                vt[c8 + 2 * j + 1][row] = (unsigned short)((unsigned)vals[j] >> 16);
            }
        }
        __syncthreads();

        // QK^T : scores[16q x 64k] per wave
        f32x4 sc[4];
#pragma unroll
        for (int t = 0; t < 4; ++t) {
            bf16x8 b0 = *reinterpret_cast<const bf16x8*>(&ks[t * 16 + r16][8 * g]);
            bf16x8 b1 = *reinterpret_cast<const bf16x8*>(&ks[t * 16 + r16][8 * g + 32]);
            f32x4 z = {};
            z = __builtin_amdgcn_mfma_f32_16x16x32_bf16(qa0, b0, z, 0, 0, 0);
            z = __builtin_amdgcn_mfma_f32_16x16x32_bf16(qa1, b1, z, 0, 0, 0);
            sc[t] = z;
        }

        // masked logits: s * scale * 0.95^|i-j|
        float pv[4][4];
        float cmax[4] = {-1e30f, -1e30f, -1e30f, -1e30f};
#pragma unroll
        for (int r = 0; r < 4; ++r) {
            int qg_ = qrow + g * 4 + r;
#pragma unroll
            for (int t = 0; t < 4; ++t) {
                int kg_ = k0 + t * 16 + r16;
                int d = qg_ - kg_;
                if (d < 0) d = -d;
                float mask = exp2f((float)d * LOG2_DECAY);
                float logit = sc[t][r] * 0.125f * mask;
                pv[t][r] = logit;
                cmax[r] = fmaxf(cmax[r], logit);
            }
        }
#pragma unroll
        for (int r = 0; r < 4; ++r) {
#pragma unroll
            for (int sh = 1; sh < 16; sh <<= 1)
                cmax[r] = fmaxf(cmax[r], __shfl_xor(cmax[r], sh));
        }
        float corr[4];
        float rsum[4] = {0.f, 0.f, 0.f, 0.f};
#pragma unroll
        for (int r = 0; r < 4; ++r) {
            float mnew = fmaxf(mrow[r], cmax[r]);
            corr[r] = exp2f((mrow[r] - mnew) * LOG2E);
            mrow[r] = mnew;
        }
#pragma unroll
        for (int t = 0; t < 4; ++t) {
#pragma unroll
            for (int r = 0; r < 4; ++r) {
                float p = exp2f((pv[t][r] - mrow[r]) * LOG2E);
                pv[t][r] = p;
                rsum[r] += p;
            }
        }
#pragma unroll
        for (int r = 0; r < 4; ++r) {
#pragma unroll
            for (int sh = 1; sh < 16; sh <<= 1)
                rsum[r] += __shfl_xor(rsum[r], sh);
            lrow[r] = lrow[r] * corr[r] + rsum[r];
        }
#pragma unroll
        for (int t = 0; t < 4; ++t) {
            acc[t][0] *= corr[0];
            acc[t][1] *= corr[1];
            acc[t][2] *= corr[2];
            acc[t][3] *= corr[3];
        }
        // P -> LDS (bf16), then PV MFMA.  Barrier for cross-lane visibility safety.
#pragma unroll
        for (int t = 0; t < 4; ++t)
#pragma unroll
            for (int r = 0; r < 4; ++r)
                ps[wave][g * 4 + r][t * 16 + r16] = f2b(pv[t][r]);
        __syncthreads();
#pragma unroll
        for (int t = 0; t < 4; ++t) {
#pragma unroll
            for (int kk0 = 0; kk0 < 64; kk0 += 32) {
                bf16x8 pa = *reinterpret_cast<const bf16x8*>(&ps[wave][r16][8 * g + kk0]);
                bf16x8 vb = *reinterpret_cast<const bf16x8*>(&vt[t * 16 + r16][8 * g + kk0]);
                acc[t] = __builtin_amdgcn_mfma_f32_16x16x32_bf16(pa, vb, acc[t], 0, 0, 0);
            }
        }
    }
    const int b = bh >> 3, h = bh & 7;
    float inv[4];
#pragma unroll
    for (int r = 0; r < 4; ++r) inv[r] = 1.0f / lrow[r];
#pragma unroll
    for (int t = 0; t < 4; ++t) {
#pragma unroll
        for (int r = 0; r < 4; ++r) {
            int qg_ = qrow + g * 4 + r;
            float o = acc[t][r] * inv[r];
            Og[((size_t)(b * L_SEQ) + qg_) * DMODEL + h * DHEAD + t * 16 + r16] = f2b(o);
        }
    }
}

extern "C" void kernel_launch(void* const* d_in, const int* in_sizes, int n_in,
                              void* d_out, int out_size, void* d_ws, size_t ws_size,
                              hipStream_t stream) {
    const float* x  = (const float*)d_in[0];
    const float* Wq = (const float*)d_in[1];
    const float* bq = (const float*)d_in[2];
    const float* Wk = (const float*)d_in[3];
    const float* bk = (const float*)d_in[4];
    const float* Wv = (const float*)d_in[5];
    const float* bv = (const float*)d_in[6];
    const float* Wo = (const float*)d_in[7];
    const float* bo = (const float*)d_in[8];
    float* out = (float*)d_out;

    const int NX = MROWS * DMODEL;        // 4,194,304
    const int NW = DMODEL * DMODEL;       // 262,144

    unsigned short* xb  = (unsigned short*)d_ws;  // also reused as attn-out buffer
    unsigned short* wqb = xb + NX;
    unsigned short* wkb = wqb + NW;
    unsigned short* wvb = wkb + NW;
    unsigned short* wob = wvb + NW;
    unsigned short* qws = wob + NW;
    unsigned short* kws = qws + NX;
    unsigned short* vws = kws + NX;

    cast_f32_to_bf16<<<(NX / 4 + 255) / 256, 256, 0, stream>>>(x, xb, NX);
    cast_f32_to_bf16<<<(NW / 4 + 255) / 256, 256, 0, stream>>>(Wq, wqb, NW);
    cast_f32_to_bf16<<<(NW / 4 + 255) / 256, 256, 0, stream>>>(Wk, wkb, NW);
    cast_f32_to_bf16<<<(NW / 4 + 255) / 256, 256, 0, stream>>>(Wv, wvb, NW);
    cast_f32_to_bf16<<<(NW / 4 + 255) / 256, 256, 0, stream>>>(Wo, wob, NW);

    dim3 gg(MROWS / 64, DMODEL / 64);
    gemm_nt<<<gg, 256, 0, stream>>>(xb, wqb, bq, qws, nullptr, 0, DMODEL, DMODEL);
    gemm_nt<<<gg, 256, 0, stream>>>(xb, wkb, bk, kws, nullptr, 0, DMODEL, DMODEL);
    gemm_nt<<<gg, 256, 0, stream>>>(xb, wvb, bv, vws, nullptr, 0, DMODEL, DMODEL);

    dim3 ga(L_SEQ / 64, NB * NH);
    attn_fused<<<ga, 256, 0, stream>>>(qws, kws, vws, xb);

    gemm_nt<<<gg, 256, 0, stream>>>(xb, wob, bo, nullptr, out, 1, DMODEL, DMODEL);
}

// Round 2
// 128.771 us; speedup vs baseline: 3.1086x; 3.1086x over previous
//
#include <hip/hip_runtime.h>
#include <hip/hip_bf16.h>

#define L_SEQ 4096
#define NB 2
#define NH 8
#define DHEAD 64
#define DMODEL 512
#define MROWS 8192
#define NTILES 64
#define KWT 4   // band half-width in 64-key tiles (256 keys); 0.95^257*5.5 ~ 1e-5

typedef __attribute__((ext_vector_type(8))) short bf16x8;
typedef __attribute__((ext_vector_type(4))) float f32x4;

#define LOG2_DECAY (-0.07400058144377693f)
#define LOG2E 1.4426950408889634f

__device__ __forceinline__ unsigned short f2b(float f) {
    __hip_bfloat16 h = __float2bfloat16(f);
    return *reinterpret_cast<unsigned short*>(&h);
}
__device__ __forceinline__ float b2f(unsigned short u) {
    unsigned int x = ((unsigned int)u) << 16;
    return *reinterpret_cast<float*>(&x);
}

__global__ void cast_f32_to_bf16(const float* __restrict__ src,
                                 unsigned short* __restrict__ dst, int n) {
    int i = (blockIdx.x * blockDim.x + threadIdx.x) * 4;
    if (i + 4 <= n) {
        float4 v = *reinterpret_cast<const float4*>(src + i);
        ushort4 o;
        o.x = f2b(v.x); o.y = f2b(v.y); o.z = f2b(v.z); o.w = f2b(v.w);
        *reinterpret_cast<ushort4*>(dst + i) = o;
    } else {
        for (; i < n; ++i) dst[i] = f2b(src[i]);
    }
}

// C[m][n] = sum_k X[m][k] * W[n][k] + bias[n]
// mode 0: write bf16 scattered to [B,H,L,Hd] layout (Q,K proj)
// mode 1: write fp32 row-major [M][N] (output proj)
// mode 2: write bf16 V TRANSPOSED to [B,H,Hd,L] + per-tile V sums TS[bh][ltile][d]
__global__ __launch_bounds__(256) void gemm_nt(const unsigned short* __restrict__ X,
                                               const unsigned short* __restrict__ W,
                                               const float* __restrict__ bias,
                                               unsigned short* __restrict__ outB,
                                               float* __restrict__ outF,
                                               float* __restrict__ TS,
                                               int mode, int Kdim, int Ndim) {
    __shared__ __align__(16) unsigned short xs[64][72];
    __shared__ __align__(16) unsigned short wls[64][72];
    const int tid = threadIdx.x;
    const int lane = tid & 63;
    const int wave = tid >> 6;
    const int r16 = lane & 15;
    const int g = lane >> 4;
    const int m0 = blockIdx.x * 64;
    const int n0 = blockIdx.y * 64;

    f32x4 acc[4] = {};
    for (int k0 = 0; k0 < Kdim; k0 += 64) {
        __syncthreads();
#pragma unroll
        for (int i = 0; i < 2; ++i) {
            int q = tid * 2 + i;
            int row = q >> 3;
            int c8 = (q & 7) * 8;
            *reinterpret_cast<int4*>(&xs[row][c8]) =
                *reinterpret_cast<const int4*>(X + (size_t)(m0 + row) * Kdim + k0 + c8);
            *reinterpret_cast<int4*>(&wls[row][c8]) =
                *reinterpret_cast<const int4*>(W + (size_t)(n0 + row) * Kdim + k0 + c8);
        }
        __syncthreads();
        bf16x8 a0 = *reinterpret_cast<const bf16x8*>(&xs[wave * 16 + r16][8 * g]);
        bf16x8 a1 = *reinterpret_cast<const bf16x8*>(&xs[wave * 16 + r16][8 * g + 32]);
#pragma unroll
        for (int t = 0; t < 4; ++t) {
            bf16x8 b0 = *reinterpret_cast<const bf16x8*>(&wls[t * 16 + r16][8 * g]);
            bf16x8 b1 = *reinterpret_cast<const bf16x8*>(&wls[t * 16 + r16][8 * g + 32]);
            acc[t] = __builtin_amdgcn_mfma_f32_16x16x32_bf16(a0, b0, acc[t], 0, 0, 0);
            acc[t] = __builtin_amdgcn_mfma_f32_16x16x32_bf16(a1, b1, acc[t], 0, 0, 0);
        }
    }

    if (mode == 2) {
        // stage transposed (bf16) tile into xs: xs[n_local][m_local]
        __syncthreads();
#pragma unroll
        for (int t = 0; t < 4; ++t)
#pragma unroll
            for (int r = 0; r < 4; ++r) {
                float v = acc[t][r] + bias[n0 + t * 16 + r16];
                xs[t * 16 + r16][wave * 16 + g * 4 + r] = f2b(v);
            }
        __syncthreads();
        const int b = m0 >> 12;
        const int l0 = m0 & 4095;
        const int h = (n0 >> 6) & 7;
        // coalesced-ish write of Vt rows: 4 threads per d-row, 16 ushorts each
        {
            int n_local = tid >> 2, part = tid & 3;
            size_t vb = ((size_t)((b * NH + h) * DHEAD + n_local)) * L_SEQ + l0 + part * 16;
            *reinterpret_cast<int4*>(outB + vb) =
                *reinterpret_cast<const int4*>(&xs[n_local][part * 16]);
            *reinterpret_cast<int4*>(outB + vb + 8) =
                *reinterpret_cast<const int4*>(&xs[n_local][part * 16 + 8]);
        }
        // per-tile V sums (from bf16-rounded values, consistent with attn band path)
        if (tid < 64) {
            float s = 0.f;
#pragma unroll
            for (int j = 0; j < 64; j += 8) {
                bf16x8 v8 = *reinterpret_cast<const bf16x8*>(&xs[tid][j]);
#pragma unroll
                for (int e = 0; e < 8; ++e) s += b2f((unsigned short)v8[e]);
            }
            TS[((size_t)(b * NH + h) * NTILES + (l0 >> 6)) * 64 + tid] = s;
        }
        return;
    }

#pragma unroll
    for (int t = 0; t < 4; ++t) {
#pragma unroll
        for (int r = 0; r < 4; ++r) {
            int m = m0 + wave * 16 + g * 4 + r;
            int n = n0 + t * 16 + r16;
            float v = acc[t][r] + bias[n];
            if (mode == 0) {
                int b = m >> 12, l = m & 4095;
                int h = n >> 6, hd = n & 63;
                outB[((size_t)(b * NH + h) * L_SEQ + l) * DHEAD + hd] = f2b(v);
            } else {
                outF[(size_t)m * Ndim + n] = v;
            }
        }
    }
}

// FS[bh][t][d] = sum of V over keys < 64*t (t = 0..64 inclusive)
__global__ void prefix_ts(const float* __restrict__ TS, float* __restrict__ FS) {
    int bh = blockIdx.x;
    int d = threadIdx.x;
    float fs = 0.f;
    FS[(size_t)bh * (NTILES + 1) * 64 + d] = 0.f;
    for (int t = 0; t < NTILES; ++t) {
        fs += TS[((size_t)bh * NTILES + t) * 64 + d];
        FS[((size_t)bh * (NTILES + 1) + t + 1) * 64 + d] = fs;
    }
}

__global__ __launch_bounds__(256) void attn_fused(const unsigned short* __restrict__ Qg,
                                                  const unsigned short* __restrict__ Kg,
                                                  const unsigned short* __restrict__ Vtg,
                                                  const float* __restrict__ FS,
                                                  unsigned short* __restrict__ Og) {
    __shared__ __align__(16) unsigned short ks[64][72];
    __shared__ __align__(16) unsigned short vt[64][72];   // [d][key]
    __shared__ __align__(16) unsigned short ps[4][16][72]; // per-wave P
    const int tid = threadIdx.x;
    const int lane = tid & 63;
    const int wave = tid >> 6;
    const int r16 = lane & 15;
    const int g = lane >> 4;
    const int bh = blockIdx.y;
    const int qt = blockIdx.x;
    const int q0 = qt * 64;
    const size_t base = (size_t)bh * L_SEQ * DHEAD;
    const unsigned short* Qb = Qg + base;
    const unsigned short* Kb = Kg + base;
    const unsigned short* Vtb = Vtg + base;  // [64][4096]
    const int qrow = q0 + wave * 16;

    bf16x8 qa0 = *reinterpret_cast<const bf16x8*>(Qb + (size_t)(qrow + r16) * DHEAD + 8 * g);
    bf16x8 qa1 = *reinterpret_cast<const bf16x8*>(Qb + (size_t)(qrow + r16) * DHEAD + 8 * g + 32);

    f32x4 acc[4] = {};
    // far-field logits are exactly 0 -> running max starts at 0
    float mrow[4] = {0.f, 0.f, 0.f, 0.f};
    float lrow[4] = {0.f, 0.f, 0.f, 0.f};

    const int t_lo = (qt - KWT) > 0 ? (qt - KWT) : 0;
    const int t_hi = (qt + 1 + KWT) < NTILES ? (qt + 1 + KWT) : NTILES;

    for (int kt = t_lo; kt < t_hi; ++kt) {
        const int k0 = kt * 64;
        __syncthreads();
#pragma unroll
        for (int i = 0; i < 2; ++i) {
            int q = tid * 2 + i;
            int row = q >> 3;
            int c8 = (q & 7) * 8;
            *reinterpret_cast<int4*>(&ks[row][c8]) =
                *reinterpret_cast<const int4*>(Kb + (size_t)(k0 + row) * DHEAD + c8);
            *reinterpret_cast<int4*>(&vt[row][c8]) =
                *reinterpret_cast<const int4*>(Vtb + (size_t)row * L_SEQ + k0 + c8);
        }
        __syncthreads();

        f32x4 sc[4];
#pragma unroll
        for (int t = 0; t < 4; ++t) {
            bf16x8 b0 = *reinterpret_cast<const bf16x8*>(&ks[t * 16 + r16][8 * g]);
            bf16x8 b1 = *reinterpret_cast<const bf16x8*>(&ks[t * 16 + r16][8 * g + 32]);
            f32x4 z = {};
            z = __builtin_amdgcn_mfma_f32_16x16x32_bf16(qa0, b0, z, 0, 0, 0);
            z = __builtin_amdgcn_mfma_f32_16x16x32_bf16(qa1, b1, z, 0, 0, 0);
            sc[t] = z;
        }

        float pv[4][4];
        float cmax[4] = {-1e30f, -1e30f, -1e30f, -1e30f};
#pragma unroll
        for (int r = 0; r < 4; ++r) {
            int qg_ = qrow + g * 4 + r;
#pragma unroll
            for (int t = 0; t < 4; ++t) {
                int kg_ = k0 + t * 16 + r16;
                int d = qg_ - kg_;
                if (d < 0) d = -d;
                float mask = exp2f((float)d * LOG2_DECAY);
                float logit = sc[t][r] * 0.125f * mask;
                pv[t][r] = logit;
                cmax[r] = fmaxf(cmax[r], logit);
            }
        }
#pragma unroll
        for (int r = 0; r < 4; ++r) {
#pragma unroll
            for (int sh = 1; sh < 16; sh <<= 1)
                cmax[r] = fmaxf(cmax[r], __shfl_xor(cmax[r], sh));
        }
        float corr[4];
        float rsum[4] = {0.f, 0.f, 0.f, 0.f};
#pragma unroll
        for (int r = 0; r < 4; ++r) {
            float mnew = fmaxf(mrow[r], cmax[r]);
            corr[r] = exp2f((mrow[r] - mnew) * LOG2E);
            mrow[r] = mnew;
        }
#pragma unroll
        for (int t = 0; t < 4; ++t) {
#pragma unroll
            for (int r = 0; r < 4; ++r) {
                float p = exp2f((pv[t][r] - mrow[r]) * LOG2E);
                pv[t][r] = p;
                rsum[r] += p;
            }
        }
#pragma unroll
        for (int r = 0; r < 4; ++r) {
#pragma unroll
            for (int sh = 1; sh < 16; sh <<= 1)
                rsum[r] += __shfl_xor(rsum[r], sh);
            lrow[r] = lrow[r] * corr[r] + rsum[r];
        }
#pragma unroll
        for (int t = 0; t < 4; ++t) {
            acc[t][0] *= corr[0];
            acc[t][1] *= corr[1];
            acc[t][2] *= corr[2];
            acc[t][3] *= corr[3];
        }
#pragma unroll
        for (int t = 0; t < 4; ++t)
#pragma unroll
            for (int r = 0; r < 4; ++r)
                ps[wave][g * 4 + r][t * 16 + r16] = f2b(pv[t][r]);
        __syncthreads();
#pragma unroll
        for (int t = 0; t < 4; ++t) {
#pragma unroll
            for (int kk0 = 0; kk0 < 64; kk0 += 32) {
                bf16x8 pa = *reinterpret_cast<const bf16x8*>(&ps[wave][r16][8 * g + kk0]);
                bf16x8 vb = *reinterpret_cast<const bf16x8*>(&vt[t * 16 + r16][8 * g + kk0]);
                acc[t] = __builtin_amdgcn_mfma_f32_16x16x32_bf16(pa, vb, acc[t], 0, 0, 0);
            }
        }
    }

    // far-field: every excluded key contributes exp(0 - m) * v_k
    const int nfar = L_SEQ - 64 * (t_hi - t_lo);
    const float* FSb = FS + (size_t)bh * (NTILES + 1) * 64;
    float em[4];
#pragma unroll
    for (int r = 0; r < 4; ++r) {
        em[r] = exp2f(-mrow[r] * LOG2E);
        lrow[r] += em[r] * (float)nfar;
    }
#pragma unroll
    for (int t = 0; t < 4; ++t) {
        int d = t * 16 + r16;
        float F = FSb[NTILES * 64 + d] - FSb[t_hi * 64 + d] + FSb[t_lo * 64 + d];
#pragma unroll
        for (int r = 0; r < 4; ++r)
            acc[t][r] += em[r] * F;
    }

    const int b = bh >> 3, h = bh & 7;
    float inv[4];
#pragma unroll
    for (int r = 0; r < 4; ++r) inv[r] = 1.0f / lrow[r];
#pragma unroll
    for (int t = 0; t < 4; ++t) {
#pragma unroll
        for (int r = 0; r < 4; ++r) {
            int qg_ = qrow + g * 4 + r;
            float o = acc[t][r] * inv[r];
            Og[((size_t)(b * L_SEQ) + qg_) * DMODEL + h * DHEAD + t * 16 + r16] = f2b(o);
        }
    }
}

extern "C" void kernel_launch(void* const* d_in, const int* in_sizes, int n_in,
                              void* d_out, int out_size, void* d_ws, size_t ws_size,
                              hipStream_t stream) {
    const float* x  = (const float*)d_in[0];
    const float* Wq = (const float*)d_in[1];
    const float* bq = (const float*)d_in[2];
    const float* Wk = (const float*)d_in[3];
    const float* bk = (const float*)d_in[4];
    const float* Wv = (const float*)d_in[5];
    const float* bv = (const float*)d_in[6];
    const float* Wo = (const float*)d_in[7];
    const float* bo = (const float*)d_in[8];
    float* out = (float*)d_out;

    const int NX = MROWS * DMODEL;        // 4,194,304
    const int NW = DMODEL * DMODEL;       // 262,144

    unsigned short* xb  = (unsigned short*)d_ws;  // reused as attn-out buffer
    unsigned short* wqb = xb + NX;
    unsigned short* wkb = wqb + NW;
    unsigned short* wvb = wkb + NW;
    unsigned short* wob = wvb + NW;
    unsigned short* qws = wob + NW;
    unsigned short* kws = qws + NX;
    unsigned short* vtg = kws + NX;               // V transposed [B,H,Hd,L]
    float* TS = (float*)(vtg + NX);               // 16*64*64
    float* FS = TS + NB * NH * NTILES * 64;       // 16*65*64

    cast_f32_to_bf16<<<(NX / 4 + 255) / 256, 256, 0, stream>>>(x, xb, NX);
    cast_f32_to_bf16<<<(NW / 4 + 255) / 256, 256, 0, stream>>>(Wq, wqb, NW);
    cast_f32_to_bf16<<<(NW / 4 + 255) / 256, 256, 0, stream>>>(Wk, wkb, NW);
    cast_f32_to_bf16<<<(NW / 4 + 255) / 256, 256, 0, stream>>>(Wv, wvb, NW);
    cast_f32_to_bf16<<<(NW / 4 + 255) / 256, 256, 0, stream>>>(Wo, wob, NW);

    dim3 gg(MROWS / 64, DMODEL / 64);
    gemm_nt<<<gg, 256, 0, stream>>>(xb, wqb, bq, qws, nullptr, nullptr, 0, DMODEL, DMODEL);
    gemm_nt<<<gg, 256, 0, stream>>>(xb, wkb, bk, kws, nullptr, nullptr, 0, DMODEL, DMODEL);
    gemm_nt<<<gg, 256, 0, stream>>>(xb, wvb, bv, vtg, nullptr, TS, 2, DMODEL, DMODEL);
    prefix_ts<<<NB * NH, 64, 0, stream>>>(TS, FS);

    dim3 ga(L_SEQ / 64, NB * NH);
    attn_fused<<<ga, 256, 0, stream>>>(qws, kws, vtg, FS, xb);

    gemm_nt<<<gg, 256, 0, stream>>>(xb, wob, bo, nullptr, out, nullptr, 1, DMODEL, DMODEL);
}

// Round 3
// 78.775 us; speedup vs baseline: 5.0815x; 1.6347x over previous
//
#include <hip/hip_runtime.h>
#include <hip/hip_bf16.h>

#define L_SEQ 4096
#define NB 2
#define NH 8
#define DHEAD 64
#define DMODEL 512
#define MROWS 8192
#define NTILES 64
#define KWT 2   // band half-width in 64-key tiles; min excluded |i-j| = 129

typedef __attribute__((ext_vector_type(8))) short bf16x8;
typedef __attribute__((ext_vector_type(4))) float f32x4;

#define LOG2_DECAY (-0.07400058144377693f)
#define LOG2E 1.4426950408889634f
#define C_SE (0.125f * LOG2E)        // scale * log2(e)
#define C_M8 (-8.0f * LOG2E)         // -M0 * log2(e)
#define EM8 3.3546262790251185e-4f   // exp(-8)

__device__ __forceinline__ unsigned short f2b(float f) {
    __hip_bfloat16 h = __float2bfloat16(f);
    return *reinterpret_cast<unsigned short*>(&h);
}
__device__ __forceinline__ float b2f(unsigned short u) {
    unsigned int x = ((unsigned int)u) << 16;
    return *reinterpret_cast<float*>(&x);
}
__device__ __forceinline__ void load_lds16(const void* g, void* l) {
    __builtin_amdgcn_global_load_lds(
        (const __attribute__((address_space(1))) unsigned int*)g,
        (__attribute__((address_space(3))) unsigned int*)l, 16, 0, 0);
}

__global__ void cast_f32_to_bf16(const float* __restrict__ src,
                                 unsigned short* __restrict__ dst, int n) {
    int i = (blockIdx.x * blockDim.x + threadIdx.x) * 4;
    if (i + 4 <= n) {
        float4 v = *reinterpret_cast<const float4*>(src + i);
        ushort4 o;
        o.x = f2b(v.x); o.y = f2b(v.y); o.z = f2b(v.z); o.w = f2b(v.w);
        *reinterpret_cast<ushort4*>(dst + i) = o;
    } else {
        for (; i < n; ++i) dst[i] = f2b(src[i]);
    }
}

__global__ void cast_w4(const float* __restrict__ w0, const float* __restrict__ w1,
                        const float* __restrict__ w2, const float* __restrict__ w3,
                        unsigned short* o0, unsigned short* o1,
                        unsigned short* o2, unsigned short* o3, int n) {
    int which = blockIdx.y;
    const float* s = which == 0 ? w0 : which == 1 ? w1 : which == 2 ? w2 : w3;
    unsigned short* o = which == 0 ? o0 : which == 1 ? o1 : which == 2 ? o2 : o3;
    int i = (blockIdx.x * blockDim.x + threadIdx.x) * 4;
    if (i + 4 <= n) {
        float4 v = *reinterpret_cast<const float4*>(s + i);
        ushort4 u;
        u.x = f2b(v.x); u.y = f2b(v.y); u.z = f2b(v.z); u.w = f2b(v.w);
        *reinterpret_cast<ushort4*>(o + i) = u;
    }
}

// ---- QKV projection GEMM: C = X * W^T + b, BM=128 BN=64 BK=64, gload_lds staging
// z=0 -> Q scatter [B,H,L,Hd], z=1 -> K scatter, z=2 -> V transposed [B,H,Hd,L] + tile sums
__global__ __launch_bounds__(256) void gemm_qkv(const unsigned short* __restrict__ X,
                                                const unsigned short* __restrict__ W0,
                                                const unsigned short* __restrict__ W1,
                                                const unsigned short* __restrict__ W2,
                                                const float* __restrict__ b0,
                                                const float* __restrict__ b1,
                                                const float* __restrict__ b2,
                                                unsigned short* __restrict__ oQ,
                                                unsigned short* __restrict__ oK,
                                                unsigned short* __restrict__ oV,
                                                float* __restrict__ TS) {
    __shared__ __align__(64) unsigned char smem[24576];
    unsigned short* As = (unsigned short*)smem;            // [128][64]
    unsigned short* Bs = (unsigned short*)(smem + 16384);  // [64][64]
    const int tid = threadIdx.x;
    const int lane = tid & 63;
    const int wave = tid >> 6;
    const int r16 = lane & 15;
    const int g = lane >> 4;
    const int wr = wave >> 1, wc = wave & 1;
    const int m0 = blockIdx.x * 128;
    const int n0 = blockIdx.y * 64;
    const int z = blockIdx.z;
    const unsigned short* W = z == 0 ? W0 : z == 1 ? W1 : W2;
    const float* bias = z == 0 ? b0 : z == 1 ? b1 : b2;
    unsigned short* outB = z == 0 ? oQ : z == 1 ? oK : oV;

    f32x4 acc[4][2] = {};
    for (int k0 = 0; k0 < DMODEL; k0 += 64) {
        __syncthreads();
#pragma unroll
        for (int c = 0; c < 6; ++c) {
            int ch = wave * 6 + c;
            const unsigned short* gp;
            unsigned char* lp;
            if (ch < 16) {
                int row = ch * 8 + (lane >> 3);
                gp = X + (size_t)(m0 + row) * DMODEL + k0 + (lane & 7) * 8;
                lp = smem + ch * 1024;
            } else {
                int row = (ch - 16) * 8 + (lane >> 3);
                gp = W + (size_t)(n0 + row) * DMODEL + k0 + (lane & 7) * 8;
                lp = smem + 16384 + (ch - 16) * 1024;
            }
            load_lds16(gp, lp);
        }
        __syncthreads();
#pragma unroll
        for (int kk = 0; kk < 2; ++kk) {
            bf16x8 bfr[2];
#pragma unroll
            for (int j = 0; j < 2; ++j)
                bfr[j] = *(const bf16x8*)(Bs + (wc * 32 + j * 16 + r16) * 64 + g * 8 + kk * 32);
#pragma unroll
            for (int i = 0; i < 4; ++i) {
                bf16x8 a = *(const bf16x8*)(As + (wr * 64 + i * 16 + r16) * 64 + g * 8 + kk * 32);
#pragma unroll
                for (int j = 0; j < 2; ++j)
                    acc[i][j] = __builtin_amdgcn_mfma_f32_16x16x32_bf16(a, bfr[j], acc[i][j], 0, 0, 0);
            }
        }
    }

    if (z == 2) {
        // V: transpose through LDS to [B,H,Hd,L] + per-64-tile sums
        __syncthreads();
        unsigned short* xsT = (unsigned short*)smem;  // [64][136]
#pragma unroll
        for (int i = 0; i < 4; ++i)
#pragma unroll
            for (int j = 0; j < 2; ++j)
#pragma unroll
                for (int r = 0; r < 4; ++r) {
                    int nl = wc * 32 + j * 16 + r16;
                    int ml = wr * 64 + i * 16 + g * 4 + r;
                    xsT[nl * 136 + ml] = f2b(acc[i][j][r] + bias[n0 + nl]);
                }
        __syncthreads();
        const int b = m0 >> 12;
        const int l0 = m0 & 4095;
        const int h = (n0 >> 6) & 7;
        {
            int drow = tid >> 2, part = tid & 3;
            size_t vb = ((size_t)((b * NH + h) * DHEAD + drow)) * L_SEQ + l0 + part * 32;
#pragma unroll
            for (int e = 0; e < 4; ++e)
                *reinterpret_cast<int4*>(outB + vb + e * 8) =
                    *reinterpret_cast<const int4*>(&xsT[drow * 136 + part * 32 + e * 8]);
        }
        if (tid < 128) {
            int d = tid & 63, half = tid >> 6;
            float s = 0.f;
#pragma unroll
            for (int jj = 0; jj < 64; jj += 8) {
                bf16x8 v8 = *reinterpret_cast<const bf16x8*>(&xsT[d * 136 + half * 64 + jj]);
#pragma unroll
                for (int e = 0; e < 8; ++e) s += b2f((unsigned short)v8[e]);
            }
            TS[((size_t)(b * NH + h) * NTILES + (l0 >> 6) + half) * 64 + d] = s;
        }
        return;
    }

#pragma unroll
    for (int i = 0; i < 4; ++i)
#pragma unroll
        for (int j = 0; j < 2; ++j)
#pragma unroll
            for (int r = 0; r < 4; ++r) {
                int m = m0 + wr * 64 + i * 16 + g * 4 + r;
                int n = n0 + wc * 32 + j * 16 + r16;
                float v = acc[i][j][r] + bias[n];
                int b = m >> 12, l = m & 4095;
                int h = n >> 6, hd = n & 63;
                outB[((size_t)(b * NH + h) * L_SEQ + l) * DHEAD + hd] = f2b(v);
            }
}

// ---- output projection GEMM: out = A * Wo^T + bo (fp32 out)
__global__ __launch_bounds__(256) void gemm_out(const unsigned short* __restrict__ X,
                                                const unsigned short* __restrict__ W,
                                                const float* __restrict__ bias,
                                                float* __restrict__ outF) {
    __shared__ __align__(64) unsigned char smem[24576];
    unsigned short* As = (unsigned short*)smem;
    unsigned short* Bs = (unsigned short*)(smem + 16384);
    const int tid = threadIdx.x;
    const int lane = tid & 63;
    const int wave = tid >> 6;
    const int r16 = lane & 15;
    const int g = lane >> 4;
    const int wr = wave >> 1, wc = wave & 1;
    const int m0 = blockIdx.x * 128;
    const int n0 = blockIdx.y * 64;

    f32x4 acc[4][2] = {};
    for (int k0 = 0; k0 < DMODEL; k0 += 64) {
        __syncthreads();
#pragma unroll
        for (int c = 0; c < 6; ++c) {
            int ch = wave * 6 + c;
            const unsigned short* gp;
            unsigned char* lp;
            if (ch < 16) {
                int row = ch * 8 + (lane >> 3);
                gp = X + (size_t)(m0 + row) * DMODEL + k0 + (lane & 7) * 8;
                lp = smem + ch * 1024;
            } else {
                int row = (ch - 16) * 8 + (lane >> 3);
                gp = W + (size_t)(n0 + row) * DMODEL + k0 + (lane & 7) * 8;
                lp = smem + 16384 + (ch - 16) * 1024;
            }
            load_lds16(gp, lp);
        }
        __syncthreads();
#pragma unroll
        for (int kk = 0; kk < 2; ++kk) {
            bf16x8 bfr[2];
#pragma unroll
            for (int j = 0; j < 2; ++j)
                bfr[j] = *(const bf16x8*)(Bs + (wc * 32 + j * 16 + r16) * 64 + g * 8 + kk * 32);
#pragma unroll
            for (int i = 0; i < 4; ++i) {
                bf16x8 a = *(const bf16x8*)(As + (wr * 64 + i * 16 + r16) * 64 + g * 8 + kk * 32);
#pragma unroll
                for (int j = 0; j < 2; ++j)
                    acc[i][j] = __builtin_amdgcn_mfma_f32_16x16x32_bf16(a, bfr[j], acc[i][j], 0, 0, 0);
            }
        }
    }
#pragma unroll
    for (int i = 0; i < 4; ++i)
#pragma unroll
        for (int j = 0; j < 2; ++j)
#pragma unroll
            for (int r = 0; r < 4; ++r) {
                int m = m0 + wr * 64 + i * 16 + g * 4 + r;
                int n = n0 + wc * 32 + j * 16 + r16;
                outF[(size_t)m * DMODEL + n] = acc[i][j][r] + bias[n];
            }
}

// FS[bh][t][d] = sum of V over keys < 64*t (t = 0..64)
__global__ void prefix_ts(const float* __restrict__ TS, float* __restrict__ FS) {
    __shared__ float segtot[4][64];
    int bh = blockIdx.x;
    int d = threadIdx.x & 63;
    int seg = threadIdx.x >> 6;
    const float* t = TS + (size_t)bh * NTILES * 64 + d;
    float vals[16];
    float run = 0.f;
#pragma unroll
    for (int i = 0; i < 16; ++i) {
        run += t[(seg * 16 + i) * 64];
        vals[i] = run;
    }
    segtot[seg][d] = run;
    __syncthreads();
    float off = 0.f;
    for (int s = 0; s < seg; ++s) off += segtot[s][d];
    float* F = FS + (size_t)bh * (NTILES + 1) * 64 + d;
    if (seg == 0) F[0] = 0.f;
#pragma unroll
    for (int i = 0; i < 16; ++i) F[(seg * 16 + i + 1) * 64] = vals[i] + off;
}

__global__ __launch_bounds__(256) void attn_fused(const unsigned short* __restrict__ Qg,
                                                  const unsigned short* __restrict__ Kg,
                                                  const unsigned short* __restrict__ Vtg,
                                                  const float* __restrict__ FS,
                                                  unsigned short* __restrict__ Og) {
    __shared__ __align__(16) unsigned short ks[64][72];
    __shared__ __align__(16) unsigned short vt[64][72];
    __shared__ __align__(16) unsigned short ps[4][16][72];
    const int tid = threadIdx.x;
    const int lane = tid & 63;
    const int wave = tid >> 6;
    const int r16 = lane & 15;
    const int g = lane >> 4;
    const int bh = blockIdx.y;
    const int qt = blockIdx.x;
    const int q0 = qt * 64;
    const size_t base = (size_t)bh * L_SEQ * DHEAD;
    const unsigned short* Qb = Qg + base;
    const unsigned short* Kb = Kg + base;
    const unsigned short* Vtb = Vtg + base;
    const int qrow = q0 + wave * 16;

    bf16x8 qa0 = *reinterpret_cast<const bf16x8*>(Qb + (size_t)(qrow + r16) * DHEAD + 8 * g);
    bf16x8 qa1 = *reinterpret_cast<const bf16x8*>(Qb + (size_t)(qrow + r16) * DHEAD + 8 * g + 32);

    const int t_lo = (qt - KWT) > 0 ? (qt - KWT) : 0;
    const int t_hi = (qt + 1 + KWT) < NTILES ? (qt + 1 + KWT) : NTILES;

    // decay factorization: decay^(D0 + dq - dk) = s0f * rowf[r] * colfInv[t]
    float rowf[4], rowfI[4], colf[4], colfI[4];
#pragma unroll
    for (int r = 0; r < 4; ++r) {
        float dq = (float)(wave * 16 + g * 4 + r);
        rowf[r] = exp2f(dq * LOG2_DECAY);
        rowfI[r] = exp2f(-dq * LOG2_DECAY);
    }
#pragma unroll
    for (int t = 0; t < 4; ++t) {
        float dk = (float)(t * 16 + r16);
        colf[t] = exp2f(dk * LOG2_DECAY);
        colfI[t] = exp2f(-dk * LOG2_DECAY);
    }
    float s0f = exp2f((float)(64 * (qt - t_lo)) * LOG2_DECAY);
    float s0b = exp2f(-(float)(64 * (qt - t_lo)) * LOG2_DECAY);
    const float stepF = exp2f(-64.f * LOG2_DECAY);
    const float stepB = exp2f(64.f * LOG2_DECAY);

    f32x4 acc[4] = {};
    float lpart[4] = {0.f, 0.f, 0.f, 0.f};

    for (int kt = t_lo; kt < t_hi; ++kt) {
        const int k0 = kt * 64;
        __syncthreads();
#pragma unroll
        for (int i = 0; i < 2; ++i) {
            int q = tid * 2 + i;
            int row = q >> 3;
            int c8 = (q & 7) * 8;
            *reinterpret_cast<int4*>(&ks[row][c8]) =
                *reinterpret_cast<const int4*>(Kb + (size_t)(k0 + row) * DHEAD + c8);
            *reinterpret_cast<int4*>(&vt[row][c8]) =
                *reinterpret_cast<const int4*>(Vtb + (size_t)row * L_SEQ + k0 + c8);
        }
        __syncthreads();

        f32x4 sc[4];
#pragma unroll
        for (int t = 0; t < 4; ++t) {
            bf16x8 b0 = *reinterpret_cast<const bf16x8*>(&ks[t * 16 + r16][8 * g]);
            bf16x8 b1 = *reinterpret_cast<const bf16x8*>(&ks[t * 16 + r16][8 * g + 32]);
            f32x4 z = {};
            z = __builtin_amdgcn_mfma_f32_16x16x32_bf16(qa0, b0, z, 0, 0, 0);
            z = __builtin_amdgcn_mfma_f32_16x16x32_bf16(qa1, b1, z, 0, 0, 0);
            sc[t] = z;
        }

        float faf[4], fab[4];
#pragma unroll
        for (int r = 0; r < 4; ++r) {
            faf[r] = s0f * rowf[r];
            fab[r] = s0b * rowfI[r];
        }
        s0f *= stepF;
        s0b *= stepB;

        // p = exp2( (sc * 0.125 * mask) * log2e - 8*log2e ), fixed max M0 = 8
#pragma unroll
        for (int t = 0; t < 4; ++t) {
#pragma unroll
            for (int r = 0; r < 4; ++r) {
                float mask = fminf(faf[r] * colfI[t], fab[r] * colf[t]);
                float x = sc[t][r] * mask;
                float p = exp2f(fmaf(x, C_SE, C_M8));
                lpart[r] += p;
                ps[wave][g * 4 + r][t * 16 + r16] = f2b(p);
            }
        }
        // ps is wave-private: no barrier needed (same-wave lgkmcnt dependency)
#pragma unroll
        for (int t = 0; t < 4; ++t) {
#pragma unroll
            for (int kk0 = 0; kk0 < 64; kk0 += 32) {
                bf16x8 pa = *reinterpret_cast<const bf16x8*>(&ps[wave][r16][8 * g + kk0]);
                bf16x8 vb = *reinterpret_cast<const bf16x8*>(&vt[t * 16 + r16][8 * g + kk0]);
                acc[t] = __builtin_amdgcn_mfma_f32_16x16x32_bf16(pa, vb, acc[t], 0, 0, 0);
            }
        }
    }

    // row sums: reduce over the 16 lanes (r16) that share a q-row
#pragma unroll
    for (int r = 0; r < 4; ++r) {
#pragma unroll
        for (int sh = 1; sh < 16; sh <<= 1)
            lpart[r] += __shfl_xor(lpart[r], sh);
    }

    const int nfar = L_SEQ - 64 * (t_hi - t_lo);
    const float* FSb = FS + (size_t)bh * (NTILES + 1) * 64;
    float lrow[4];
#pragma unroll
    for (int r = 0; r < 4; ++r) lrow[r] = lpart[r] + EM8 * (float)nfar;
#pragma unroll
    for (int t = 0; t < 4; ++t) {
        int d = t * 16 + r16;
        float F = FSb[NTILES * 64 + d] - FSb[t_hi * 64 + d] + FSb[t_lo * 64 + d];
#pragma unroll
        for (int r = 0; r < 4; ++r) acc[t][r] += EM8 * F;
    }

    const int b = bh >> 3, h = bh & 7;
    float inv[4];
#pragma unroll
    for (int r = 0; r < 4; ++r) inv[r] = 1.0f / lrow[r];
#pragma unroll
    for (int t = 0; t < 4; ++t) {
#pragma unroll
        for (int r = 0; r < 4; ++r) {
            int qg_ = qrow + g * 4 + r;
            float o = acc[t][r] * inv[r];
            Og[((size_t)(b * L_SEQ) + qg_) * DMODEL + h * DHEAD + t * 16 + r16] = f2b(o);
        }
    }
}

extern "C" void kernel_launch(void* const* d_in, const int* in_sizes, int n_in,
                              void* d_out, int out_size, void* d_ws, size_t ws_size,
                              hipStream_t stream) {
    const float* x  = (const float*)d_in[0];
    const float* Wq = (const float*)d_in[1];
    const float* bq = (const float*)d_in[2];
    const float* Wk = (const float*)d_in[3];
    const float* bk = (const float*)d_in[4];
    const float* Wv = (const float*)d_in[5];
    const float* bv = (const float*)d_in[6];
    const float* Wo = (const float*)d_in[7];
    const float* bo = (const float*)d_in[8];
    float* out = (float*)d_out;

    const int NX = MROWS * DMODEL;
    const int NW = DMODEL * DMODEL;

    unsigned short* xb  = (unsigned short*)d_ws;  // x bf16; later reused as attn output
    unsigned short* wqb = xb + NX;
    unsigned short* wkb = wqb + NW;
    unsigned short* wvb = wkb + NW;
    unsigned short* wob = wvb + NW;
    unsigned short* qws = wob + NW;
    unsigned short* kws = qws + NX;
    unsigned short* vtg = kws + NX;               // V transposed [B,H,Hd,L]
    float* TS = (float*)(vtg + NX);
    float* FS = TS + NB * NH * NTILES * 64;

    cast_f32_to_bf16<<<(NX / 4 + 255) / 256, 256, 0, stream>>>(x, xb, NX);
    dim3 cw((NW / 4 + 255) / 256, 4);
    cast_w4<<<cw, 256, 0, stream>>>(Wq, Wk, Wv, Wo, wqb, wkb, wvb, wob, NW);

    dim3 gq(MROWS / 128, DMODEL / 64, 3);
    gemm_qkv<<<gq, 256, 0, stream>>>(xb, wqb, wkb, wvb, bq, bk, bv, qws, kws, vtg, TS);
    prefix_ts<<<NB * NH, 256, 0, stream>>>(TS, FS);

    dim3 ga(L_SEQ / 64, NB * NH);
    attn_fused<<<ga, 256, 0, stream>>>(qws, kws, vtg, FS, xb);

    dim3 go(MROWS / 128, DMODEL / 64);
    gemm_out<<<go, 256, 0, stream>>>(xb, wob, bo, out);
}

// Round 4
// 70.176 us; speedup vs baseline: 5.7042x; 1.1225x over previous
//
#include <hip/hip_runtime.h>
#include <hip/hip_bf16.h>

#define L_SEQ 4096
#define NB 2
#define NH 8
#define DHEAD 64
#define DMODEL 512
#define MROWS 8192
#define NTILES 64
#define KWT 2   // band half-width in 64-key tiles; min excluded |i-j| = 129

typedef __attribute__((ext_vector_type(8))) short bf16x8;
typedef __attribute__((ext_vector_type(4))) float f32x4;

#define LOG2_DECAY (-0.07400058144377693f)
#define LOG2E 1.4426950408889634f
#define C_SE (0.125f * LOG2E)        // scale * log2(e), folded into decay factors
#define C_M8 (-8.0f * LOG2E)         // -M0 * log2(e)
#define EM8 3.3546262790251185e-4f   // exp(-8)

typedef int4 ld128;

__device__ __forceinline__ unsigned short f2b(float f) {
    __hip_bfloat16 h = __float2bfloat16(f);
    return *reinterpret_cast<unsigned short*>(&h);
}
__device__ __forceinline__ float b2f(unsigned short u) {
    unsigned int x = ((unsigned int)u) << 16;
    return *reinterpret_cast<float*>(&x);
}
__device__ __forceinline__ void load_lds16(const void* g, void* l) {
    __builtin_amdgcn_global_load_lds(
        (const __attribute__((address_space(1))) unsigned int*)g,
        (__attribute__((address_space(3))) unsigned int*)l, 16, 0, 0);
}

__global__ void cast_all(const float* __restrict__ x,
                         const float* __restrict__ Wq, const float* __restrict__ Wk,
                         const float* __restrict__ Wv, const float* __restrict__ Wo,
                         unsigned short* __restrict__ xb,
                         unsigned short* __restrict__ wqb, unsigned short* __restrict__ wkb,
                         unsigned short* __restrict__ wvb, unsigned short* __restrict__ wob) {
    const int NX = MROWS * DMODEL;
    const int NW = DMODEL * DMODEL;
    int i4 = (blockIdx.x * blockDim.x + threadIdx.x) * 4;
    const float* s;
    unsigned short* o;
    int off;
    if (i4 < NX) { s = x; o = xb; off = i4; }
    else {
        int j = i4 - NX;
        int w = j >> 18;           // NW = 2^18
        off = j & (NW - 1);
        s = w == 0 ? Wq : w == 1 ? Wk : w == 2 ? Wv : Wo;
        o = w == 0 ? wqb : w == 1 ? wkb : w == 2 ? wvb : wob;
    }
    float4 v = *reinterpret_cast<const float4*>(s + off);
    ushort4 u;
    u.x = f2b(v.x); u.y = f2b(v.y); u.z = f2b(v.z); u.w = f2b(v.w);
    *reinterpret_cast<ushort4*>(o + off) = u;
}

// fused QKV projection: one block computes Q,K,V for a 128x64 tile (A staged once)
__global__ __launch_bounds__(256, 2) void gemm_qkv(const unsigned short* __restrict__ X,
                                                   const unsigned short* __restrict__ W0,
                                                   const unsigned short* __restrict__ W1,
                                                   const unsigned short* __restrict__ W2,
                                                   const float* __restrict__ b0,
                                                   const float* __restrict__ b1,
                                                   const float* __restrict__ b2,
                                                   unsigned short* __restrict__ oQ,
                                                   unsigned short* __restrict__ oK,
                                                   unsigned short* __restrict__ oV,
                                                   float* __restrict__ TS) {
    __shared__ __align__(64) unsigned char smem[40960];
    unsigned short* As = (unsigned short*)smem;            // [128][64]
    const int tid = threadIdx.x;
    const int lane = tid & 63;
    const int wave = tid >> 6;
    const int r16 = lane & 15;
    const int g = lane >> 4;
    const int wr = wave >> 1, wc = wave & 1;
    const int m0 = blockIdx.x * 128;
    const int n0 = blockIdx.y * 64;

    f32x4 acc[3][4][2] = {};
    for (int k0 = 0; k0 < DMODEL; k0 += 64) {
        __syncthreads();
#pragma unroll
        for (int c = 0; c < 10; ++c) {
            int ch = wave * 10 + c;
            const unsigned short* gp;
            unsigned char* lp;
            if (ch < 16) {
                int row = ch * 8 + (lane >> 3);
                gp = X + (size_t)(m0 + row) * DMODEL + k0 + (lane & 7) * 8;
                lp = smem + ch * 1024;
            } else {
                int zz = (ch - 16) >> 3;
                int sub = (ch - 16) & 7;
                int row = sub * 8 + (lane >> 3);
                const unsigned short* W = zz == 0 ? W0 : zz == 1 ? W1 : W2;
                gp = W + (size_t)(n0 + row) * DMODEL + k0 + (lane & 7) * 8;
                lp = smem + 16384 + zz * 8192 + sub * 1024;
            }
            load_lds16(gp, lp);
        }
        __syncthreads();
#pragma unroll
        for (int kk = 0; kk < 2; ++kk) {
            bf16x8 a[4];
#pragma unroll
            for (int i = 0; i < 4; ++i)
                a[i] = *(const bf16x8*)(As + (wr * 64 + i * 16 + r16) * 64 + g * 8 + kk * 32);
#pragma unroll
            for (int zz = 0; zz < 3; ++zz) {
                const unsigned short* Bs = (const unsigned short*)(smem + 16384 + zz * 8192);
#pragma unroll
                for (int j = 0; j < 2; ++j) {
                    bf16x8 bfr = *(const bf16x8*)(Bs + (wc * 32 + j * 16 + r16) * 64 + g * 8 + kk * 32);
#pragma unroll
                    for (int i = 0; i < 4; ++i)
                        acc[zz][i][j] = __builtin_amdgcn_mfma_f32_16x16x32_bf16(a[i], bfr, acc[zz][i][j], 0, 0, 0);
                }
            }
        }
    }

    const int b = m0 >> 12;
    const int l0 = m0 & 4095;
    const int h = (n0 >> 6) & 7;

    // Q, K scatter epilogues
#pragma unroll
    for (int zz = 0; zz < 2; ++zz) {
        const float* bias = zz == 0 ? b0 : b1;
        unsigned short* outB = zz == 0 ? oQ : oK;
#pragma unroll
        for (int i = 0; i < 4; ++i)
#pragma unroll
            for (int j = 0; j < 2; ++j)
#pragma unroll
                for (int r = 0; r < 4; ++r) {
                    int m = m0 + wr * 64 + i * 16 + g * 4 + r;
                    int n = n0 + wc * 32 + j * 16 + r16;
                    float v = acc[zz][i][j][r] + bias[n];
                    int l = m & 4095, hd = n & 63;
                    outB[((size_t)(b * NH + h) * L_SEQ + l) * DHEAD + hd] = f2b(v);
                }
    }

    // V: transpose through LDS -> [B,H,Hd,L] + per-tile sums TS
    __syncthreads();
    unsigned short* xsT = (unsigned short*)smem;  // [64][136]
#pragma unroll
    for (int i = 0; i < 4; ++i)
#pragma unroll
        for (int j = 0; j < 2; ++j)
#pragma unroll
            for (int r = 0; r < 4; ++r) {
                int nl = wc * 32 + j * 16 + r16;
                int ml = wr * 64 + i * 16 + g * 4 + r;
                xsT[nl * 136 + ml] = f2b(acc[2][i][j][r] + b2[n0 + nl]);
            }
    __syncthreads();
    {
        int drow = tid >> 2, part = tid & 3;
        size_t vb = ((size_t)((b * NH + h) * DHEAD + drow)) * L_SEQ + l0 + part * 32;
#pragma unroll
        for (int e = 0; e < 4; ++e)
            *reinterpret_cast<int4*>(oV + vb + e * 8) =
                *reinterpret_cast<const int4*>(&xsT[drow * 136 + part * 32 + e * 8]);
    }
    if (tid < 128) {
        int d = tid & 63, half = tid >> 6;
        float s = 0.f;
#pragma unroll
        for (int jj = 0; jj < 64; jj += 8) {
            bf16x8 v8 = *reinterpret_cast<const bf16x8*>(&xsT[d * 136 + half * 64 + jj]);
#pragma unroll
            for (int e = 0; e < 8; ++e) s += b2f((unsigned short)v8[e]);
        }
        TS[((size_t)(b * NH + h) * NTILES + (l0 >> 6) + half) * 64 + d] = s;
    }
}

// output projection: out = A * Wo^T + bo (fp32)
__global__ __launch_bounds__(256) void gemm_out(const unsigned short* __restrict__ X,
                                                const unsigned short* __restrict__ W,
                                                const float* __restrict__ bias,
                                                float* __restrict__ outF) {
    __shared__ __align__(64) unsigned char smem[24576];
    unsigned short* As = (unsigned short*)smem;
    unsigned short* Bs = (unsigned short*)(smem + 16384);
    const int tid = threadIdx.x;
    const int lane = tid & 63;
    const int wave = tid >> 6;
    const int r16 = lane & 15;
    const int g = lane >> 4;
    const int wr = wave >> 1, wc = wave & 1;
    const int m0 = blockIdx.x * 128;
    const int n0 = blockIdx.y * 64;

    f32x4 acc[4][2] = {};
    for (int k0 = 0; k0 < DMODEL; k0 += 64) {
        __syncthreads();
#pragma unroll
        for (int c = 0; c < 6; ++c) {
            int ch = wave * 6 + c;
            const unsigned short* gp;
            unsigned char* lp;
            if (ch < 16) {
                int row = ch * 8 + (lane >> 3);
                gp = X + (size_t)(m0 + row) * DMODEL + k0 + (lane & 7) * 8;
                lp = smem + ch * 1024;
            } else {
                int row = (ch - 16) * 8 + (lane >> 3);
                gp = W + (size_t)(n0 + row) * DMODEL + k0 + (lane & 7) * 8;
                lp = smem + 16384 + (ch - 16) * 1024;
            }
            load_lds16(gp, lp);
        }
        __syncthreads();
#pragma unroll
        for (int kk = 0; kk < 2; ++kk) {
            bf16x8 bfr[2];
#pragma unroll
            for (int j = 0; j < 2; ++j)
                bfr[j] = *(const bf16x8*)(Bs + (wc * 32 + j * 16 + r16) * 64 + g * 8 + kk * 32);
#pragma unroll
            for (int i = 0; i < 4; ++i) {
                bf16x8 a = *(const bf16x8*)(As + (wr * 64 + i * 16 + r16) * 64 + g * 8 + kk * 32);
#pragma unroll
                for (int j = 0; j < 2; ++j)
                    acc[i][j] = __builtin_amdgcn_mfma_f32_16x16x32_bf16(a, bfr[j], acc[i][j], 0, 0, 0);
            }
        }
    }
#pragma unroll
    for (int i = 0; i < 4; ++i)
#pragma unroll
        for (int j = 0; j < 2; ++j)
#pragma unroll
            for (int r = 0; r < 4; ++r) {
                int m = m0 + wr * 64 + i * 16 + g * 4 + r;
                int n = n0 + wc * 32 + j * 16 + r16;
                outF[(size_t)m * DMODEL + n] = acc[i][j][r] + bias[n];
            }
}

__global__ __launch_bounds__(256) void attn_fused(const unsigned short* __restrict__ Qg,
                                                  const unsigned short* __restrict__ Kg,
                                                  const unsigned short* __restrict__ Vtg,
                                                  const float* __restrict__ TS,
                                                  unsigned short* __restrict__ Og) {
    __shared__ __align__(16) unsigned short ks[64][72];
    __shared__ __align__(16) unsigned short vt[64][72];
    __shared__ __align__(16) unsigned short ps[4][16][72];
    __shared__ float Fp[4][64];
    __shared__ float Fsh[64];
    const int tid = threadIdx.x;
    const int lane = tid & 63;
    const int wave = tid >> 6;
    const int r16 = lane & 15;
    const int g = lane >> 4;
    const int bh = blockIdx.y;
    const int qt = blockIdx.x;
    const int q0 = qt * 64;
    const size_t base = (size_t)bh * L_SEQ * DHEAD;
    const unsigned short* Qb = Qg + base;
    const unsigned short* Kb = Kg + base;
    const unsigned short* Vtb = Vtg + base;
    const int qrow = q0 + wave * 16;

    bf16x8 qa0 = *reinterpret_cast<const bf16x8*>(Qb + (size_t)(qrow + r16) * DHEAD + 8 * g);
    bf16x8 qa1 = *reinterpret_cast<const bf16x8*>(Qb + (size_t)(qrow + r16) * DHEAD + 8 * g + 32);

    const int t_lo = (qt - KWT) > 0 ? (qt - KWT) : 0;
    const int t_hi = (qt + 1 + KWT) < NTILES ? (qt + 1 + KWT) : NTILES;

    // decay factorization with C_SE folded in: mask_se = min(s0f*rowf*colfI, s0b*rowfI*colf)
    float rowf[4], rowfI[4], colf[4], colfI[4];
#pragma unroll
    for (int r = 0; r < 4; ++r) {
        float dq = (float)(wave * 16 + g * 4 + r);
        rowf[r] = exp2f(dq * LOG2_DECAY);
        rowfI[r] = exp2f(-dq * LOG2_DECAY);
    }
#pragma unroll
    for (int t = 0; t < 4; ++t) {
        float dk = (float)(t * 16 + r16);
        colf[t] = exp2f(dk * LOG2_DECAY);
        colfI[t] = exp2f(-dk * LOG2_DECAY);
    }
    float s0f = C_SE * exp2f((float)(64 * (qt - t_lo)) * LOG2_DECAY);
    float s0b = C_SE * exp2f(-(float)(64 * (qt - t_lo)) * LOG2_DECAY);
    const float stepF = exp2f(-64.f * LOG2_DECAY);
    const float stepB = exp2f(64.f * LOG2_DECAY);

    f32x4 acc[4] = {};
    float lpart[4] = {0.f, 0.f, 0.f, 0.f};

    // register-staged K/V tile (T14 async-split)
    const int srow = tid >> 2;
    const int scol = (tid & 3) * 16;
    int4 kr0, kr1, vr0, vr1;
#define ISSUE(KT) { \
    const unsigned short* kp = Kb + ((size_t)((KT) * 64 + srow)) * DHEAD + scol; \
    kr0 = *(const int4*)kp; kr1 = *(const int4*)(kp + 8); \
    const unsigned short* vp = Vtb + (size_t)srow * L_SEQ + (KT) * 64 + scol; \
    vr0 = *(const int4*)vp; vr1 = *(const int4*)(vp + 8); }

    ISSUE(t_lo);
    for (int kt = t_lo; kt < t_hi; ++kt) {
        __builtin_amdgcn_s_barrier();   // all waves done reading LDS from prev iter
        *(int4*)&ks[srow][scol] = kr0;
        *(int4*)&ks[srow][scol + 8] = kr1;
        *(int4*)&vt[srow][scol] = vr0;
        *(int4*)&vt[srow][scol + 8] = vr1;
        if (kt + 1 < t_hi) ISSUE(kt + 1);   // next tile's loads fly across the barrier
        asm volatile("s_waitcnt lgkmcnt(0)" ::: "memory");
        __builtin_amdgcn_s_barrier();

        f32x4 sc[4];
        __builtin_amdgcn_s_setprio(1);
#pragma unroll
        for (int t = 0; t < 4; ++t) {
            bf16x8 b0 = *reinterpret_cast<const bf16x8*>(&ks[t * 16 + r16][8 * g]);
            bf16x8 b1 = *reinterpret_cast<const bf16x8*>(&ks[t * 16 + r16][8 * g + 32]);
            f32x4 z = {};
            z = __builtin_amdgcn_mfma_f32_16x16x32_bf16(qa0, b0, z, 0, 0, 0);
            z = __builtin_amdgcn_mfma_f32_16x16x32_bf16(qa1, b1, z, 0, 0, 0);
            sc[t] = z;
        }
        __builtin_amdgcn_s_setprio(0);

        float faf[4], fab[4];
#pragma unroll
        for (int r = 0; r < 4; ++r) {
            faf[r] = s0f * rowf[r];
            fab[r] = s0b * rowfI[r];
        }
        s0f *= stepF;
        s0b *= stepB;

#pragma unroll
        for (int t = 0; t < 4; ++t) {
#pragma unroll
            for (int r = 0; r < 4; ++r) {
                float mask_se = fminf(faf[r] * colfI[t], fab[r] * colf[t]);
                float p = exp2f(fmaf(sc[t][r], mask_se, C_M8));
                lpart[r] += p;
                ps[wave][g * 4 + r][t * 16 + r16] = f2b(p);
            }
        }
        // ps is wave-private; same-wave lgkmcnt dependency suffices
        __builtin_amdgcn_s_setprio(1);
#pragma unroll
        for (int t = 0; t < 4; ++t) {
#pragma unroll
            for (int kk0 = 0; kk0 < 64; kk0 += 32) {
                bf16x8 pa = *reinterpret_cast<const bf16x8*>(&ps[wave][r16][8 * g + kk0]);
                bf16x8 vb = *reinterpret_cast<const bf16x8*>(&vt[t * 16 + r16][8 * g + kk0]);
                acc[t] = __builtin_amdgcn_mfma_f32_16x16x32_bf16(pa, vb, acc[t], 0, 0, 0);
            }
        }
        __builtin_amdgcn_s_setprio(0);
    }
#undef ISSUE

    // far-field V sum from TS, computed cooperatively (no prefix kernel)
    {
        int d = tid & 63, c = tid >> 6;
        const float* tsb = TS + (size_t)bh * NTILES * 64 + d;
        float f = 0.f;
        for (int t = c; t < NTILES; t += 4)
            if (t < t_lo || t >= t_hi) f += tsb[t * 64];
        Fp[c][d] = f;
    }
    __syncthreads();
    if (tid < 64) Fsh[tid] = Fp[0][tid] + Fp[1][tid] + Fp[2][tid] + Fp[3][tid];
    __syncthreads();

#pragma unroll
    for (int r = 0; r < 4; ++r) {
#pragma unroll
        for (int sh = 1; sh < 16; sh <<= 1)
            lpart[r] += __shfl_xor(lpart[r], sh);
    }

    const int nfar = L_SEQ - 64 * (t_hi - t_lo);
    float lrow[4];
#pragma unroll
    for (int r = 0; r < 4; ++r) lrow[r] = lpart[r] + EM8 * (float)nfar;
#pragma unroll
    for (int t = 0; t < 4; ++t) {
        float F = Fsh[t * 16 + r16];
#pragma unroll
        for (int r = 0; r < 4; ++r) acc[t][r] += EM8 * F;
    }

    const int b = bh >> 3, h = bh & 7;
    float inv[4];
#pragma unroll
    for (int r = 0; r < 4; ++r) inv[r] = 1.0f / lrow[r];
#pragma unroll
    for (int t = 0; t < 4; ++t) {
#pragma unroll
        for (int r = 0; r < 4; ++r) {
            int qg_ = qrow + g * 4 + r;
            float o = acc[t][r] * inv[r];
            Og[((size_t)(b * L_SEQ) + qg_) * DMODEL + h * DHEAD + t * 16 + r16] = f2b(o);
        }
    }
}

extern "C" void kernel_launch(void* const* d_in, const int* in_sizes, int n_in,
                              void* d_out, int out_size, void* d_ws, size_t ws_size,
                              hipStream_t stream) {
    const float* x  = (const float*)d_in[0];
    const float* Wq = (const float*)d_in[1];
    const float* bq = (const float*)d_in[2];
    const float* Wk = (const float*)d_in[3];
    const float* bk = (const float*)d_in[4];
    const float* Wv = (const float*)d_in[5];
    const float* bv = (const float*)d_in[6];
    const float* Wo = (const float*)d_in[7];
    const float* bo = (const float*)d_in[8];
    float* out = (float*)d_out;

    const int NX = MROWS * DMODEL;
    const int NW = DMODEL * DMODEL;

    unsigned short* xb  = (unsigned short*)d_ws;  // x bf16; reused as attn output
    unsigned short* wqb = xb + NX;
    unsigned short* wkb = wqb + NW;
    unsigned short* wvb = wkb + NW;
    unsigned short* wob = wvb + NW;
    unsigned short* qws = wob + NW;
    unsigned short* kws = qws + NX;
    unsigned short* vtg = kws + NX;               // V transposed [B,H,Hd,L]
    float* TS = (float*)(vtg + NX);

    const int totalCast = (NX + 4 * NW) / 4;
    cast_all<<<totalCast / 256, 256, 0, stream>>>(x, Wq, Wk, Wv, Wo, xb, wqb, wkb, wvb, wob);

    dim3 gq(MROWS / 128, DMODEL / 64);
    gemm_qkv<<<gq, 256, 0, stream>>>(xb, wqb, wkb, wvb, bq, bk, bv, qws, kws, vtg, TS);

    dim3 ga(L_SEQ / 64, NB * NH);
    attn_fused<<<ga, 256, 0, stream>>>(qws, kws, vtg, TS, xb);

    dim3 go(MROWS / 128, DMODEL / 64);
    gemm_out<<<go, 256, 0, stream>>>(xb, wob, bo, out);
}